// Round 13
// baseline (206.951 us; speedup 1.0000x reference)
//
#include <hip/hip_runtime.h>
#include <hip/hip_bf16.h>

#define KS 5
#define NCH 32
#define IMH 256
#define IMW 256
#define TW 32
#define TH 8
#define HALO_W (TW + 4)
#define HALO_H (TH + 4)
#define HW (IMH * IMW)
#define OC_CHUNK 8

#define CHUNK 4
#define NCHUNK (NCH / CHUNK)
#define TILE_ELEMS (CHUNK * HALO_H * HALO_W)
#define LOADS ((TILE_ELEMS + 255) / 256)   // 7

__device__ __forceinline__ float sigmoidf_(float x) {
    return 1.0f / (1.0f + __expf(-x));
}

// ---------------------------------------------------------------------------
// R10 structure (proven 114.7us) + ONE delta: depth-2 staging pipeline.
// Rationale: R6/R11/R12 falsified occupancy/instruction-count/manual-prefetch
// theories; the remaining untested lever is HBM staging latency depth. R10's
// depth-1 gives ~1 compute phase of cover (~marginal vs ~900cy HBM latency
// with 4 blocks/CU contending); depth-2 gives two phases. Phase 3's first two
// chunks additionally issue BEFORE the KSA MLP (~5.7k cycles of cover).
// Register discipline unchanged: per-channel results retire to per-thread LDS
// columns inside ROLLED loops; pre0/pre1 are the only loop-carried arrays.
// ---------------------------------------------------------------------------
__global__ __launch_bounds__(256) void cika_fused(
    const float* __restrict__ lower, const float* __restrict__ upper,
    const float* __restrict__ kca_dw_w, const float* __restrict__ kca_dw_b,
    const float* __restrict__ kca_m1_w, const float* __restrict__ kca_m1_b,
    const float* __restrict__ kca_m2_w, const float* __restrict__ kca_m2_b,
    const float* __restrict__ ksa_dw_w, const float* __restrict__ ksa_dw_b,
    const float* __restrict__ ksa_m1_w, const float* __restrict__ ksa_m1_b,
    const float* __restrict__ ksa_m2_w, const float* __restrict__ ksa_m2_b,
    const float* __restrict__ low_dyn_w, const float* __restrict__ low_dyn_b,
    const float* __restrict__ low_pw_w, const float* __restrict__ low_pw_b,
    const float* __restrict__ up_dw_w, const float* __restrict__ up_dw_b,
    const float* __restrict__ up_pw_w, const float* __restrict__ up_pw_b,
    float* __restrict__ out_low, float* __restrict__ out_up)
{
    __shared__ float tile[TILE_ELEMS];                 //  6912 B
    __shared__ __hip_bfloat16 dwk_td_lds[NCH][256];    // 16 KB: relu(ksa_dw), later td
    __shared__ __hip_bfloat16 dwu_lds[NCH][256];       // 16 KB: up_dw result

    const int tid = threadIdx.x;
    const int tx = tid & (TW - 1);
    const int ty = tid >> 5;
    const int tile_x = blockIdx.x * TW;
    const int tile_y = blockIdx.y * TH;
    const int n = blockIdx.z;
    const int x = tile_x + tx, y = tile_y + ty;
    const int pix = y * IMW + x;

    const float* lob = lower + (size_t)n * NCH * HW;
    const float* upb = upper + (size_t)n * NCH * HW;

    // hoisted staging geometry (shared by both passes)
    int goff[LOADS];
    bool gok[LOADS];
    #pragma unroll
    for (int l = 0; l < LOADS; ++l) {
        const int idx = tid + l * 256;
        int c = idx / (HALO_H * HALO_W);
        int r = idx - c * (HALO_H * HALO_W);
        int hy = r / HALO_W, hx = r - hy * HALO_W;
        int gy = tile_y + hy - 2, gx = tile_x + hx - 2;
        gok[l] = (idx < TILE_ELEMS) && (gy >= 0) && (gy < IMH) && (gx >= 0) && (gx < IMW);
        goff[l] = c * HW + gy * IMW + gx;
    }

    // ================= Phase 1: upper pass (rolled, depth-2 pipeline) =======
    {
        float pre0[LOADS], pre1[LOADS];
        #pragma unroll
        for (int l = 0; l < LOADS; ++l)
            pre0[l] = gok[l] ? upb[(size_t)0 + goff[l]] : 0.0f;
        #pragma unroll
        for (int l = 0; l < LOADS; ++l)
            pre1[l] = gok[l] ? upb[(size_t)CHUNK * HW + goff[l]] : 0.0f;

        #pragma unroll 1
        for (int ck = 0; ck < NCHUNK; ++ck) {
            __syncthreads();
            #pragma unroll
            for (int l = 0; l < LOADS; ++l) {
                const int idx = tid + l * 256;
                if (idx < TILE_ELEMS) tile[idx] = pre0[l];
            }
            __syncthreads();
            #pragma unroll
            for (int l = 0; l < LOADS; ++l) pre0[l] = pre1[l];
            if (ck + 2 < NCHUNK) {
                const size_t base = (size_t)(ck + 2) * CHUNK * HW;
                #pragma unroll
                for (int l = 0; l < LOADS; ++l)
                    pre1[l] = gok[l] ? upb[base + goff[l]] : 0.0f;
            }
            const int c0 = ck * CHUNK;
            #pragma unroll
            for (int cc = 0; cc < CHUNK; ++cc) {
                const int c = c0 + cc;
                float ak = ksa_dw_b[c];
                float au = up_dw_b[c];
                const float* tp = tile + cc * (HALO_H * HALO_W) + ty * HALO_W + tx;
                #pragma unroll
                for (int i = 0; i < KS; ++i)
                    #pragma unroll
                    for (int j = 0; j < KS; ++j) {
                        float wv = tp[i * HALO_W + j];
                        ak = fmaf(wv, ksa_dw_w[c * 25 + i * KS + j], ak);
                        au = fmaf(wv, up_dw_w[c * 25 + i * KS + j], au);
                    }
                dwk_td_lds[c][tid] = __float2bfloat16(fmaxf(ak, 0.0f));
                dwu_lds[c][tid]    = __float2bfloat16(au);
            }
        }
    }

    // Issue lower-pass chunks 0,1 loads NOW: the KSA MLP (~2850 FMA) covers
    // their HBM latency.
    float lpre0[LOADS], lpre1[LOADS];
    #pragma unroll
    for (int l = 0; l < LOADS; ++l)
        lpre0[l] = gok[l] ? lob[(size_t)0 + goff[l]] : 0.0f;
    #pragma unroll
    for (int l = 0; l < LOADS; ++l)
        lpre1[l] = gok[l] ? lob[(size_t)CHUNK * HW + goff[l]] : 0.0f;

    // ================= Phase 2: KSA MLP 32->50(relu)->25(sigmoid) ===========
    float ksa[25];
    {
        float dwk[NCH];
        #pragma unroll
        for (int c = 0; c < NCH; ++c)
            dwk[c] = __bfloat162float(dwk_td_lds[c][tid]);
        #pragma unroll
        for (int k = 0; k < 25; ++k) ksa[k] = ksa_m2_b[k];
        for (int h = 0; h < 50; ++h) {
            float hv = ksa_m1_b[h];
            #pragma unroll
            for (int c = 0; c < NCH; ++c)
                hv = fmaf(ksa_m1_w[h * NCH + c], dwk[c], hv);
            hv = fmaxf(hv, 0.0f);
            #pragma unroll
            for (int k = 0; k < 25; ++k)
                ksa[k] = fmaf(ksa_m2_w[k * 50 + h], hv, ksa[k]);
        }
        #pragma unroll
        for (int k = 0; k < 25; ++k) ksa[k] = sigmoidf_(ksa[k]);
    }
    // dwk_td_lds now dead as dwk -> reused for td (same-thread columns only).

    // ================= Phase 3: lower pass (rolled, depth-2, online hv8) ====
    float hv8[8];
    #pragma unroll
    for (int h = 0; h < 8; ++h) hv8[h] = kca_m1_b[h];
    {
        #pragma unroll 1
        for (int ck = 0; ck < NCHUNK; ++ck) {
            __syncthreads();
            #pragma unroll
            for (int l = 0; l < LOADS; ++l) {
                const int idx = tid + l * 256;
                if (idx < TILE_ELEMS) tile[idx] = lpre0[l];
            }
            __syncthreads();
            #pragma unroll
            for (int l = 0; l < LOADS; ++l) lpre0[l] = lpre1[l];
            if (ck + 2 < NCHUNK) {
                const size_t base = (size_t)(ck + 2) * CHUNK * HW;
                #pragma unroll
                for (int l = 0; l < LOADS; ++l)
                    lpre1[l] = gok[l] ? lob[base + goff[l]] : 0.0f;
            }
            const int c0 = ck * CHUNK;
            #pragma unroll
            for (int cc = 0; cc < CHUNK; ++cc) {
                const int c = c0 + cc;
                float ad = kca_dw_b[c];
                float td = low_dyn_b[c];
                const float* tp = tile + cc * (HALO_H * HALO_W) + ty * HALO_W + tx;
                #pragma unroll
                for (int i = 0; i < KS; ++i)
                    #pragma unroll
                    for (int j = 0; j < KS; ++j) {
                        float wv = tp[i * HALO_W + j];
                        ad = fmaf(wv, kca_dw_w[c * 25 + i * KS + j], ad);
                        td = fmaf(wv * low_dyn_w[c * 25 + i * KS + j], ksa[i * KS + j], td);
                    }
                ad = fmaxf(ad, 0.0f);
                #pragma unroll
                for (int h = 0; h < 8; ++h)
                    hv8[h] = fmaf(kca_m1_w[h * NCH + c], ad, hv8[h]);
                dwk_td_lds[c][tid] = __float2bfloat16(td);
            }
        }
    }

    // ================= Phase 4: out_low = low_pw @ td + b ===================
    {
        float tdv[NCH];
        #pragma unroll
        for (int c = 0; c < NCH; ++c)
            tdv[c] = __bfloat162float(dwk_td_lds[c][tid]);
        float* ol = out_low + (size_t)n * NCH * HW + pix;
        #pragma unroll
        for (int oc = 0; oc < NCH / OC_CHUNK; ++oc) {
            float acc[OC_CHUNK];
            #pragma unroll
            for (int oo = 0; oo < OC_CHUNK; ++oo)
                acc[oo] = low_pw_b[oc * OC_CHUNK + oo];
            #pragma unroll
            for (int c = 0; c < NCH; ++c)
                #pragma unroll
                for (int oo = 0; oo < OC_CHUNK; ++oo)
                    acc[oo] = fmaf(low_pw_w[(oc * OC_CHUNK + oo) * NCH + c], tdv[c], acc[oo]);
            #pragma unroll
            for (int oo = 0; oo < OC_CHUNK; ++oo)
                ol[(size_t)(oc * OC_CHUNK + oo) * HW] = acc[oo];
        }
    }

    // ================= Phase 5: KCA finish ==================================
    float kca[NCH];
    #pragma unroll
    for (int h = 0; h < 8; ++h) hv8[h] = fmaxf(hv8[h], 0.0f);
    #pragma unroll
    for (int k = 0; k < NCH; ++k) {
        float a = kca_m2_b[k];
        #pragma unroll
        for (int h = 0; h < 8; ++h)
            a = fmaf(kca_m2_w[k * 8 + h], hv8[h], a);
        kca[k] = sigmoidf_(a);
    }

    // ================= Phase 6: up path =====================================
    {
        float t2[NCH];
        #pragma unroll
        for (int c = 0; c < NCH; ++c)
            t2[c] = __bfloat162float(dwu_lds[c][tid]) * kca[c];
        float* ou = out_up + (size_t)n * NCH * HW + pix;
        #pragma unroll
        for (int oc = 0; oc < NCH / OC_CHUNK; ++oc) {
            float acc[OC_CHUNK];
            #pragma unroll
            for (int oo = 0; oo < OC_CHUNK; ++oo)
                acc[oo] = up_pw_b[oc * OC_CHUNK + oo];
            #pragma unroll
            for (int c = 0; c < NCH; ++c)
                #pragma unroll
                for (int oo = 0; oo < OC_CHUNK; ++oo)
                    acc[oo] = fmaf(up_pw_w[(oc * OC_CHUNK + oo) * NCH + c], t2[c], acc[oo]);
            #pragma unroll
            for (int oo = 0; oo < OC_CHUNK; ++oo)
                ou[(size_t)(oc * OC_CHUNK + oo) * HW] = acc[oo];
        }
    }
}

extern "C" void kernel_launch(void* const* d_in, const int* in_sizes, int n_in,
                              void* d_out, int out_size, void* d_ws, size_t ws_size,
                              hipStream_t stream) {
    const float* lower    = (const float*)d_in[0];
    const float* upper    = (const float*)d_in[1];
    const float* kca_dw_w = (const float*)d_in[2];
    const float* kca_dw_b = (const float*)d_in[3];
    const float* kca_m1_w = (const float*)d_in[4];
    const float* kca_m1_b = (const float*)d_in[5];
    const float* kca_m2_w = (const float*)d_in[6];
    const float* kca_m2_b = (const float*)d_in[7];
    const float* ksa_dw_w = (const float*)d_in[8];
    const float* ksa_dw_b = (const float*)d_in[9];
    const float* ksa_m1_w = (const float*)d_in[10];
    const float* ksa_m1_b = (const float*)d_in[11];
    const float* ksa_m2_w = (const float*)d_in[12];
    const float* ksa_m2_b = (const float*)d_in[13];
    const float* low_dyn_w = (const float*)d_in[14];
    const float* low_dyn_b = (const float*)d_in[15];
    const float* low_pw_w  = (const float*)d_in[16];
    const float* low_pw_b  = (const float*)d_in[17];
    const float* up_dw_w   = (const float*)d_in[18];
    const float* up_dw_b   = (const float*)d_in[19];
    const float* up_pw_w   = (const float*)d_in[20];
    const float* up_pw_b   = (const float*)d_in[21];

    const int N = in_sizes[0] / (NCH * HW);
    float* out_low = (float*)d_out;
    float* out_up  = (float*)d_out + (size_t)N * NCH * HW;

    dim3 grid(IMW / TW, IMH / TH, N);
    cika_fused<<<grid, dim3(256), 0, stream>>>(
        lower, upper,
        kca_dw_w, kca_dw_b, kca_m1_w, kca_m1_b, kca_m2_w, kca_m2_b,
        ksa_dw_w, ksa_dw_b, ksa_m1_w, ksa_m1_b, ksa_m2_w, ksa_m2_b,
        low_dyn_w, low_dyn_b, low_pw_w, low_pw_b,
        up_dw_w, up_dw_b, up_pw_w, up_pw_b,
        out_low, out_up);
}

// Round 14
// 113.932 us; speedup vs baseline: 1.8164x; 1.8164x over previous
//
#include <hip/hip_runtime.h>
#include <hip/hip_bf16.h>

#define KS 5
#define NCH 32
#define IMH 256
#define IMW 256
#define TW 32
#define TH 8
#define HALO_W (TW + 4)
#define HALO_H (TH + 4)
#define HW (IMH * IMW)
#define OC_CHUNK 8

#define CHUNK 4
#define NCHUNK (NCH / CHUNK)
#define TILE_ELEMS (CHUNK * HALO_H * HALO_W)
#define LOADS ((TILE_ELEMS + 255) / 256)   // 7

__device__ __forceinline__ float sigmoidf_(float x) {
    return 1.0f / (1.0f + __expf(-x));
}

// ---------------------------------------------------------------------------
// Fully fused CIKA forward, one kernel. EXACT R10 revert (proven 114.7 us).
// R11 (pk_fma), R12 (tap prefetch), R13 (depth-2 staging) all regressed:
// the compiler's schedule at VGPR=64 / 4 blocks/CU is a sharp local optimum;
// source-level reordering degrades achieved occupancy (46% -> 26%).
// Register discipline (R3-R9 lessons): per-channel results retire immediately
// to per-thread LDS columns; no register array incrementally written across
// an UNROLLED staging loop; chunk loops ROLLED so hv8[8] is plain loop state.
// LDS: tile 6.9K + dwk/td (aliased) 16K + dwu 16K = 38.9 KB -> 4 blocks/CU;
// grid 1024 = fully resident. T14 depth-1 prefetch: next-chunk loads issue
// before compute, drain at next iteration's barrier.
// ---------------------------------------------------------------------------
__global__ __launch_bounds__(256) void cika_fused(
    const float* __restrict__ lower, const float* __restrict__ upper,
    const float* __restrict__ kca_dw_w, const float* __restrict__ kca_dw_b,
    const float* __restrict__ kca_m1_w, const float* __restrict__ kca_m1_b,
    const float* __restrict__ kca_m2_w, const float* __restrict__ kca_m2_b,
    const float* __restrict__ ksa_dw_w, const float* __restrict__ ksa_dw_b,
    const float* __restrict__ ksa_m1_w, const float* __restrict__ ksa_m1_b,
    const float* __restrict__ ksa_m2_w, const float* __restrict__ ksa_m2_b,
    const float* __restrict__ low_dyn_w, const float* __restrict__ low_dyn_b,
    const float* __restrict__ low_pw_w, const float* __restrict__ low_pw_b,
    const float* __restrict__ up_dw_w, const float* __restrict__ up_dw_b,
    const float* __restrict__ up_pw_w, const float* __restrict__ up_pw_b,
    float* __restrict__ out_low, float* __restrict__ out_up)
{
    __shared__ float tile[TILE_ELEMS];                 //  6912 B
    __shared__ __hip_bfloat16 dwk_td_lds[NCH][256];    // 16 KB: relu(ksa_dw), later td
    __shared__ __hip_bfloat16 dwu_lds[NCH][256];       // 16 KB: up_dw result

    const int tid = threadIdx.x;
    const int tx = tid & (TW - 1);
    const int ty = tid >> 5;
    const int tile_x = blockIdx.x * TW;
    const int tile_y = blockIdx.y * TH;
    const int n = blockIdx.z;
    const int x = tile_x + tx, y = tile_y + ty;
    const int pix = y * IMW + x;

    const float* lob = lower + (size_t)n * NCH * HW;
    const float* upb = upper + (size_t)n * NCH * HW;

    // hoisted staging geometry (shared by both passes)
    int goff[LOADS];
    bool gok[LOADS];
    #pragma unroll
    for (int l = 0; l < LOADS; ++l) {
        const int idx = tid + l * 256;
        int c = idx / (HALO_H * HALO_W);
        int r = idx - c * (HALO_H * HALO_W);
        int hy = r / HALO_W, hx = r - hy * HALO_W;
        int gy = tile_y + hy - 2, gx = tile_x + hx - 2;
        gok[l] = (idx < TILE_ELEMS) && (gy >= 0) && (gy < IMH) && (gx >= 0) && (gx < IMW);
        goff[l] = c * HW + gy * IMW + gx;
    }

    // ================= Phase 1: upper pass (rolled) =================
    {
        float pre[LOADS];
        #pragma unroll
        for (int l = 0; l < LOADS; ++l)
            pre[l] = gok[l] ? upb[(size_t)0 + goff[l]] : 0.0f;

        #pragma unroll 1
        for (int ck = 0; ck < NCHUNK; ++ck) {
            __syncthreads();
            #pragma unroll
            for (int l = 0; l < LOADS; ++l) {
                const int idx = tid + l * 256;
                if (idx < TILE_ELEMS) tile[idx] = pre[l];
            }
            __syncthreads();
            if (ck + 1 < NCHUNK) {
                const size_t base = (size_t)(ck + 1) * CHUNK * HW;
                #pragma unroll
                for (int l = 0; l < LOADS; ++l)
                    pre[l] = gok[l] ? upb[base + goff[l]] : 0.0f;
            }
            const int c0 = ck * CHUNK;
            #pragma unroll
            for (int cc = 0; cc < CHUNK; ++cc) {
                const int c = c0 + cc;
                float ak = ksa_dw_b[c];
                float au = up_dw_b[c];
                const float* tp = tile + cc * (HALO_H * HALO_W) + ty * HALO_W + tx;
                #pragma unroll
                for (int i = 0; i < KS; ++i)
                    #pragma unroll
                    for (int j = 0; j < KS; ++j) {
                        float wv = tp[i * HALO_W + j];
                        ak = fmaf(wv, ksa_dw_w[c * 25 + i * KS + j], ak);
                        au = fmaf(wv, up_dw_w[c * 25 + i * KS + j], au);
                    }
                dwk_td_lds[c][tid] = __float2bfloat16(fmaxf(ak, 0.0f));
                dwu_lds[c][tid]    = __float2bfloat16(au);
            }
        }
    }

    // ================= Phase 2: KSA MLP 32->50(relu)->25(sigmoid) =================
    float ksa[25];
    {
        float dwk[NCH];
        #pragma unroll
        for (int c = 0; c < NCH; ++c)
            dwk[c] = __bfloat162float(dwk_td_lds[c][tid]);
        #pragma unroll
        for (int k = 0; k < 25; ++k) ksa[k] = ksa_m2_b[k];
        for (int h = 0; h < 50; ++h) {
            float hv = ksa_m1_b[h];
            #pragma unroll
            for (int c = 0; c < NCH; ++c)
                hv = fmaf(ksa_m1_w[h * NCH + c], dwk[c], hv);
            hv = fmaxf(hv, 0.0f);
            #pragma unroll
            for (int k = 0; k < 25; ++k)
                ksa[k] = fmaf(ksa_m2_w[k * 50 + h], hv, ksa[k]);
        }
        #pragma unroll
        for (int k = 0; k < 25; ++k) ksa[k] = sigmoidf_(ksa[k]);
    }
    // dwk_td_lds now dead as dwk -> reused below for td (same-thread
    // column access only, so no barrier needed for the aliasing).

    // ================= Phase 3: lower pass (rolled), online hv8 =================
    float hv8[8];
    #pragma unroll
    for (int h = 0; h < 8; ++h) hv8[h] = kca_m1_b[h];
    {
        float pre[LOADS];
        #pragma unroll
        for (int l = 0; l < LOADS; ++l)
            pre[l] = gok[l] ? lob[(size_t)0 + goff[l]] : 0.0f;

        #pragma unroll 1
        for (int ck = 0; ck < NCHUNK; ++ck) {
            __syncthreads();
            #pragma unroll
            for (int l = 0; l < LOADS; ++l) {
                const int idx = tid + l * 256;
                if (idx < TILE_ELEMS) tile[idx] = pre[l];
            }
            __syncthreads();
            if (ck + 1 < NCHUNK) {
                const size_t base = (size_t)(ck + 1) * CHUNK * HW;
                #pragma unroll
                for (int l = 0; l < LOADS; ++l)
                    pre[l] = gok[l] ? lob[base + goff[l]] : 0.0f;
            }
            const int c0 = ck * CHUNK;
            #pragma unroll
            for (int cc = 0; cc < CHUNK; ++cc) {
                const int c = c0 + cc;
                float ad = kca_dw_b[c];
                float td = low_dyn_b[c];
                const float* tp = tile + cc * (HALO_H * HALO_W) + ty * HALO_W + tx;
                #pragma unroll
                for (int i = 0; i < KS; ++i)
                    #pragma unroll
                    for (int j = 0; j < KS; ++j) {
                        float wv = tp[i * HALO_W + j];
                        ad = fmaf(wv, kca_dw_w[c * 25 + i * KS + j], ad);
                        td = fmaf(wv * low_dyn_w[c * 25 + i * KS + j], ksa[i * KS + j], td);
                    }
                ad = fmaxf(ad, 0.0f);
                #pragma unroll
                for (int h = 0; h < 8; ++h)
                    hv8[h] = fmaf(kca_m1_w[h * NCH + c], ad, hv8[h]);
                dwk_td_lds[c][tid] = __float2bfloat16(td);   // td into aliased array
            }
        }
    }

    // ================= Phase 4: out_low = low_pw @ td + b =================
    {
        float tdv[NCH];
        #pragma unroll
        for (int c = 0; c < NCH; ++c)
            tdv[c] = __bfloat162float(dwk_td_lds[c][tid]);
        float* ol = out_low + (size_t)n * NCH * HW + pix;
        #pragma unroll
        for (int oc = 0; oc < NCH / OC_CHUNK; ++oc) {
            float acc[OC_CHUNK];
            #pragma unroll
            for (int oo = 0; oo < OC_CHUNK; ++oo)
                acc[oo] = low_pw_b[oc * OC_CHUNK + oo];
            #pragma unroll
            for (int c = 0; c < NCH; ++c)
                #pragma unroll
                for (int oo = 0; oo < OC_CHUNK; ++oo)
                    acc[oo] = fmaf(low_pw_w[(oc * OC_CHUNK + oo) * NCH + c], tdv[c], acc[oo]);
            #pragma unroll
            for (int oo = 0; oo < OC_CHUNK; ++oo)
                ol[(size_t)(oc * OC_CHUNK + oo) * HW] = acc[oo];
        }
    }

    // ================= Phase 5: KCA finish =================
    float kca[NCH];
    #pragma unroll
    for (int h = 0; h < 8; ++h) hv8[h] = fmaxf(hv8[h], 0.0f);
    #pragma unroll
    for (int k = 0; k < NCH; ++k) {
        float a = kca_m2_b[k];
        #pragma unroll
        for (int h = 0; h < 8; ++h)
            a = fmaf(kca_m2_w[k * 8 + h], hv8[h], a);
        kca[k] = sigmoidf_(a);
    }

    // ================= Phase 6: up path =================
    {
        float t2[NCH];
        #pragma unroll
        for (int c = 0; c < NCH; ++c)
            t2[c] = __bfloat162float(dwu_lds[c][tid]) * kca[c];
        float* ou = out_up + (size_t)n * NCH * HW + pix;
        #pragma unroll
        for (int oc = 0; oc < NCH / OC_CHUNK; ++oc) {
            float acc[OC_CHUNK];
            #pragma unroll
            for (int oo = 0; oo < OC_CHUNK; ++oo)
                acc[oo] = up_pw_b[oc * OC_CHUNK + oo];
            #pragma unroll
            for (int c = 0; c < NCH; ++c)
                #pragma unroll
                for (int oo = 0; oo < OC_CHUNK; ++oo)
                    acc[oo] = fmaf(up_pw_w[(oc * OC_CHUNK + oo) * NCH + c], t2[c], acc[oo]);
            #pragma unroll
            for (int oo = 0; oo < OC_CHUNK; ++oo)
                ou[(size_t)(oc * OC_CHUNK + oo) * HW] = acc[oo];
        }
    }
}

extern "C" void kernel_launch(void* const* d_in, const int* in_sizes, int n_in,
                              void* d_out, int out_size, void* d_ws, size_t ws_size,
                              hipStream_t stream) {
    const float* lower    = (const float*)d_in[0];
    const float* upper    = (const float*)d_in[1];
    const float* kca_dw_w = (const float*)d_in[2];
    const float* kca_dw_b = (const float*)d_in[3];
    const float* kca_m1_w = (const float*)d_in[4];
    const float* kca_m1_b = (const float*)d_in[5];
    const float* kca_m2_w = (const float*)d_in[6];
    const float* kca_m2_b = (const float*)d_in[7];
    const float* ksa_dw_w = (const float*)d_in[8];
    const float* ksa_dw_b = (const float*)d_in[9];
    const float* ksa_m1_w = (const float*)d_in[10];
    const float* ksa_m1_b = (const float*)d_in[11];
    const float* ksa_m2_w = (const float*)d_in[12];
    const float* ksa_m2_b = (const float*)d_in[13];
    const float* low_dyn_w = (const float*)d_in[14];
    const float* low_dyn_b = (const float*)d_in[15];
    const float* low_pw_w  = (const float*)d_in[16];
    const float* low_pw_b  = (const float*)d_in[17];
    const float* up_dw_w   = (const float*)d_in[18];
    const float* up_dw_b   = (const float*)d_in[19];
    const float* up_pw_w   = (const float*)d_in[20];
    const float* up_pw_b   = (const float*)d_in[21];

    const int N = in_sizes[0] / (NCH * HW);
    float* out_low = (float*)d_out;
    float* out_up  = (float*)d_out + (size_t)N * NCH * HW;

    dim3 grid(IMW / TW, IMH / TH, N);
    cika_fused<<<grid, dim3(256), 0, stream>>>(
        lower, upper,
        kca_dw_w, kca_dw_b, kca_m1_w, kca_m1_b, kca_m2_w, kca_m2_b,
        ksa_dw_w, ksa_dw_b, ksa_m1_w, ksa_m1_b, ksa_m2_w, ksa_m2_b,
        low_dyn_w, low_dyn_b, low_pw_w, low_pw_b,
        up_dw_w, up_dw_b, up_pw_w, up_pw_b,
        out_low, out_up);
}